// Round 1
// baseline (402.499 us; speedup 1.0000x reference)
//
#include <hip/hip_runtime.h>
#include <cstdint>

#define N_FACES_C 40000
#define N_EDGES_C 60000
#define CH        512

typedef __bf16 bf16_t;
typedef __bf16 bf16x8 __attribute__((ext_vector_type(8)));
typedef float  f32x4  __attribute__((ext_vector_type(4)));
static_assert(sizeof(bf16x8) == 16, "bf16x8 must be 16B");

// ---------------- runtime input-dtype detection ----------------
__global__ void detect_dtype(const unsigned int* __restrict__ vals_bits, int* __restrict__ flag) {
  if (blockIdx.x == 0 && threadIdx.x == 0)
    *flag = (vals_bits[0] == 0x3F803F80u) ? 1 : 0;  // 1 = inputs are bf16
}

__device__ __forceinline__ float load_val(const void* vals, int i, bool isbf16) {
  return isbf16 ? (float)((const bf16_t*)vals)[i] : ((const float*)vals)[i];
}

__device__ __forceinline__ float fast_sigmoid(float z) {
  // v_exp_f32 + v_rcp_f32: ~1ulp each, error ~1e-7 abs on (0,1) — far below bf16 ulp
  float e = __builtin_amdgcn_exp2f(z * -1.44269504f);
  return __builtin_amdgcn_rcpf(1.0f + e);
}

// ---------------- degree + count (atomic histogram) ----------------
__global__ void count_deg_kernel(const int* __restrict__ ei, const int* __restrict__ fi,
                                 const void* __restrict__ vals, int nnz,
                                 float* __restrict__ deg_e, float* __restrict__ deg_f,
                                 int* __restrict__ cnt_e, int* __restrict__ cnt_f,
                                 const int* __restrict__ flag) {
  int i = blockIdx.x * 256 + threadIdx.x;
  if (i >= nnz) return;
  bool isb = (*flag != 0);
  float v = load_val(vals, i, isb);
  int e = ei[i], f = fi[i];
  atomicAdd(&deg_e[e], v);
  atomicAdd(&deg_f[f], v);
  atomicAdd(&cnt_e[e], 1);
  atomicAdd(&cnt_f[f], 1);
}

// ---------------- batched 3-phase exclusive scan (e and f in one grid) ----------------
__global__ void scan_part2(const int* __restrict__ cntE, int nE, int* __restrict__ bsumE,
                           const int* __restrict__ cntF, int nF, int* __restrict__ bsumF,
                           int nbE) {
  __shared__ int wsum[4];
  int bx = blockIdx.x;
  const int* cnt; int n; int* bsum; int b;
  if (bx < nbE) { cnt = cntE; n = nE; bsum = bsumE; b = bx; }
  else          { cnt = cntF; n = nF; bsum = bsumF; b = bx - nbE; }
  int t = threadIdx.x;
  int lane = t & 63, wave = t >> 6;
  int base = b * 1024 + t * 4;
  int s = 0;
#pragma unroll
  for (int k = 0; k < 4; ++k) {
    int idx = base + k;
    if (idx < n) s += cnt[idx];
  }
#pragma unroll
  for (int o = 32; o > 0; o >>= 1) s += __shfl_down(s, o);
  if (lane == 0) wsum[wave] = s;
  __syncthreads();
  if (t == 0) bsum[b] = wsum[0] + wsum[1] + wsum[2] + wsum[3];
}

__global__ void scan_bsums2(int* __restrict__ bsumE, int nbE, int* __restrict__ bsumF, int nbF) {
  int wave = threadIdx.x >> 6;          // 0 -> e, 1 -> f
  int lane = threadIdx.x & 63;
  int* bsum = wave ? bsumF : bsumE;
  int nb    = wave ? nbF   : nbE;
  int orig = (lane < nb) ? bsum[lane] : 0;
  int v = orig;
#pragma unroll
  for (int o = 1; o < 64; o <<= 1) {
    int u = __shfl_up(v, o);
    if (lane >= o) v += u;
  }
  if (lane < nb) bsum[lane] = v - orig;  // exclusive
}

__global__ void scan_final2(const int* __restrict__ cntE, int nE, const int* __restrict__ bsumE,
                            int* __restrict__ ptrE, int* __restrict__ curE,
                            const int* __restrict__ cntF, int nF, const int* __restrict__ bsumF,
                            int* __restrict__ ptrF, int* __restrict__ curF, int nbE) {
  __shared__ int wsum[4];
  int bx = blockIdx.x;
  const int* cnt; int n; const int* bsum; int* ptr; int* cur; int b;
  if (bx < nbE) { cnt = cntE; n = nE; bsum = bsumE; ptr = ptrE; cur = curE; b = bx; }
  else          { cnt = cntF; n = nF; bsum = bsumF; ptr = ptrF; cur = curF; b = bx - nbE; }
  int t = threadIdx.x;
  int lane = t & 63, wave = t >> 6;
  int base = b * 1024 + t * 4;
  int c[4];
  int s = 0;
#pragma unroll
  for (int k = 0; k < 4; ++k) {
    int idx = base + k;
    c[k] = (idx < n) ? cnt[idx] : 0;
    s += c[k];
  }
  int v = s;
#pragma unroll
  for (int o = 1; o < 64; o <<= 1) {
    int u = __shfl_up(v, o);
    if (lane >= o) v += u;
  }
  if (lane == 63) wsum[wave] = v;
  __syncthreads();
  int woff = 0;
  for (int w = 0; w < wave; ++w) woff += wsum[w];
  int run = bsum[b] + woff + (v - s);
#pragma unroll
  for (int k = 0; k < 4; ++k) {
    int idx = base + k;
    if (idx < n) {
      ptr[idx] = run;
      cur[idx] = run;
      run += c[k];
      if (idx == n - 1) ptr[n] = run;
    }
  }
}

// ---------------- CSR fill (both directions in one pass) ----------------
__global__ void csr_fill(const int* __restrict__ ei, const int* __restrict__ fi,
                         const void* __restrict__ vals, int nnz,
                         int* __restrict__ cur_e, int* __restrict__ col_e, float* __restrict__ val_e,
                         int* __restrict__ cur_f, int* __restrict__ col_f, float* __restrict__ val_f,
                         const int* __restrict__ flag) {
  int i = blockIdx.x * 256 + threadIdx.x;
  if (i >= nnz) return;
  bool isb = (*flag != 0);
  int e = ei[i], f = fi[i];
  float v = load_val(vals, i, isb);
  int p = atomicAdd(&cur_e[e], 1);
  col_e[p] = f; val_e[p] = v;
  int q = atomicAdd(&cur_f[f], 1);
  col_f[q] = e; val_f[q] = v;
}

// ---------------- 512x512 transpose (both W1 and W2 in one grid via z) ----------------
__global__ void transposeW2(const void* __restrict__ W1, bf16_t* __restrict__ W1t,
                            const void* __restrict__ W2, bf16_t* __restrict__ W2t,
                            const int* __restrict__ flag) {
  __shared__ bf16_t tile[32][33];
  bool isb = (*flag != 0);
  const void* W = blockIdx.z ? W2 : W1;
  bf16_t*    Wt = blockIdx.z ? W2t : W1t;
  int bx = blockIdx.x * 32, by = blockIdx.y * 32;
  int tx = threadIdx.x, ty = threadIdx.y;  // (32, 8)
#pragma unroll
  for (int r = 0; r < 32; r += 8) {
    size_t idx = (size_t)(by + ty + r) * CH + bx + tx;
    tile[ty + r][tx] = isb ? ((const bf16_t*)W)[idx] : (bf16_t)((const float*)W)[idx];
  }
  __syncthreads();
#pragma unroll
  for (int r = 0; r < 32; r += 8)
    Wt[(size_t)(bx + ty + r) * CH + by + tx] = tile[tx][ty + r];
}

// ---------------- CSR-gather SpMM + deg-divide + sigmoid (one wave per row), bf16 in/out --------
// h[row,:] = sigmoid( (sum_p val[p] * X[col[p],:]) / deg[row] )
__global__ void spmm_sig(const int* __restrict__ ptr, const int* __restrict__ cols,
                         const float* __restrict__ vals, const bf16_t* __restrict__ X,
                         const float* __restrict__ deg, bf16_t* __restrict__ Y,
                         int nRows, int nCols, int nnz) {
  int row = blockIdx.x * 4 + (threadIdx.x >> 6);
  if (row >= nRows) return;
  int lane = threadIdx.x & 63;
  int beg = ptr[row], end = ptr[row + 1];
  if (beg < 0) beg = 0;
  if (end > nnz) end = nnz;
  float acc[8];
#pragma unroll
  for (int t = 0; t < 8; ++t) acc[t] = 0.f;
  const int lofs = lane * 8;
  for (int p = beg; p < end; ++p) {
    int c = cols[p];
    if ((unsigned)c >= (unsigned)nCols) c = 0;
    float v = vals[p];
    bf16x8 xv = *(const bf16x8*)(X + (size_t)c * CH + lofs);
#pragma unroll
    for (int t = 0; t < 8; ++t) acc[t] += v * (float)xv[t];
  }
  float d = deg[row];
  float invd = (d != 0.f) ? (1.0f / d) : 0.f;
  bf16x8 o;
#pragma unroll
  for (int t = 0; t < 8; ++t) o[t] = (bf16_t)fast_sigmoid(acc[t] * invd);
  *(bf16x8*)(Y + (size_t)row * CH + lofs) = o;
}

// ---------------- GEMM t = A @ Bt^T, A = x (f32 reg-staged+converted, or bf16 direct) ----------
// No activation; bf16 output. LDS layout identical to verified gemm_sig:
// LDS row = 64 bf16 = 8 x 16B segs; slot(row, s) holds global seg s ^ (row & 7).
__global__ __launch_bounds__(256)
void gemm_xw(const void* __restrict__ A, const bf16_t* __restrict__ Bt,
             bf16_t* __restrict__ C, int M, const int* __restrict__ flag) {
  __shared__ __align__(16) bf16_t As[128 * 64];  // 16 KB
  __shared__ __align__(16) bf16_t Bs[128 * 64];  // 16 KB
  const int tid  = threadIdx.x;
  const int lane = tid & 63;
  const int wave = tid >> 6;
  const int r0 = blockIdx.y * 128;
  const int c0 = blockIdx.x * 128;
  const int wr = (wave >> 1) * 64;
  const int wc = (wave & 1) * 64;
  const int q   = lane >> 4;
  const int l16 = lane & 15;
  const int srow_base = wave * 8 + (lane >> 3);
  const int sslot = lane & 7;
  const bool ab = (*flag != 0);  // A already bf16

  f32x4 acc[4][4];
#pragma unroll
  for (int i = 0; i < 4; ++i)
#pragma unroll
    for (int j = 0; j < 4; ++j)
      acc[i][j] = (f32x4){0.f, 0.f, 0.f, 0.f};

  for (int kt = 0; kt < 8; ++kt) {   // K = 512 = 8 * 64
    const int kb = kt * 64;
    if (ab) {
      const bf16_t* Ab = (const bf16_t*)A;
#pragma unroll
      for (int i = 0; i < 4; ++i) {
        const int lr = i * 32 + srow_base;
        const int gofs = (sslot ^ (lr & 7)) * 8;
        int ra = r0 + lr; if (ra > M - 1) ra = M - 1;
        __builtin_amdgcn_global_load_lds((const __attribute__((address_space(1))) void*)(Ab + (size_t)ra * CH + kb + gofs),
                                         (__attribute__((address_space(3))) void*)(As + (i * 32 + wave * 8) * 64), 16, 0, 0);
        __builtin_amdgcn_global_load_lds((const __attribute__((address_space(1))) void*)(Bt + (size_t)(c0 + lr) * CH + kb + gofs),
                                         (__attribute__((address_space(3))) void*)(Bs + (i * 32 + wave * 8) * 64), 16, 0, 0);
      }
    } else {
      const float* Af = (const float*)A;
#pragma unroll
      for (int i = 0; i < 4; ++i) {
        const int lr = i * 32 + srow_base;
        const int gofs = (sslot ^ (lr & 7)) * 8;
        int ra = r0 + lr; if (ra > M - 1) ra = M - 1;
        const float* src = Af + (size_t)ra * CH + kb + gofs;
        float4 a = *(const float4*)src;
        float4 b = *(const float4*)(src + 4);
        bf16x8 v;
        v[0] = (bf16_t)a.x; v[1] = (bf16_t)a.y; v[2] = (bf16_t)a.z; v[3] = (bf16_t)a.w;
        v[4] = (bf16_t)b.x; v[5] = (bf16_t)b.y; v[6] = (bf16_t)b.z; v[7] = (bf16_t)b.w;
        *(bf16x8*)(As + lr * 64 + sslot * 8) = v;
        __builtin_amdgcn_global_load_lds((const __attribute__((address_space(1))) void*)(Bt + (size_t)(c0 + lr) * CH + kb + gofs),
                                         (__attribute__((address_space(3))) void*)(Bs + (i * 32 + wave * 8) * 64), 16, 0, 0);
      }
    }
    __syncthreads();

#pragma unroll
    for (int kk = 0; kk < 2; ++kk) {
      const int slot = (kk * 4 + q) ^ (l16 & 7);
      const int ro = slot * 8;
      bf16x8 af[4], bfv[4];
#pragma unroll
      for (int i = 0; i < 4; ++i)
        af[i] = *(const bf16x8*)(As + (wr + i * 16 + l16) * 64 + ro);
#pragma unroll
      for (int j = 0; j < 4; ++j)
        bfv[j] = *(const bf16x8*)(Bs + (wc + j * 16 + l16) * 64 + ro);
#pragma unroll
      for (int i = 0; i < 4; ++i)
#pragma unroll
        for (int j = 0; j < 4; ++j)
          acc[i][j] = __builtin_amdgcn_mfma_f32_16x16x32_bf16(af[i], bfv[j], acc[i][j], 0, 0, 0);
    }
    __syncthreads();
  }

  // C/D layout: col=lane&15, row=(lane>>4)*4+reg  (m89-verified)
#pragma unroll
  for (int i = 0; i < 4; ++i) {
#pragma unroll
    for (int r = 0; r < 4; ++r) {
      int row = r0 + wr + i * 16 + q * 4 + r;
      if (row < M) {
#pragma unroll
        for (int j = 0; j < 4; ++j) {
          int col = c0 + wc + j * 16 + l16;
          C[(size_t)row * CH + col] = (bf16_t)acc[i][j][r];
        }
      }
    }
  }
}

// ---------------- fused gather-GEMM: out = sigmoid( ((B2^T h)/deg_f) @ W2 ) --------------------
// A-tile rows are computed on the fly: A[ra, k] = (sum_p val[p] * H[col[p], k]) / deg[ra].
// Gather metadata (up to 4 nnz) hoisted into registers across all 8 K-tiles; fallback loop
// handles rows with more nnz. Numerically identical to the old spmm_div -> gemm_sig pair.
__global__ __launch_bounds__(256)
void gemm_gather_sig(const int* __restrict__ ptrR, const int* __restrict__ colsR,
                     const float* __restrict__ valsR, const bf16_t* __restrict__ H,
                     const float* __restrict__ deg, const bf16_t* __restrict__ Bt,
                     void* __restrict__ C, int M, int nColsH, int nnz,
                     const int* __restrict__ flag) {
  __shared__ __align__(16) bf16_t As[128 * 64];  // 16 KB
  __shared__ __align__(16) bf16_t Bs[128 * 64];  // 16 KB
  const int tid  = threadIdx.x;
  const int lane = tid & 63;
  const int wave = tid >> 6;
  const int r0 = blockIdx.y * 128;
  const int c0 = blockIdx.x * 128;
  const int wr = (wave >> 1) * 64;
  const int wc = (wave & 1) * 64;
  const int q   = lane >> 4;
  const int l16 = lane & 15;
  const int srow_base = wave * 8 + (lane >> 3);
  const int sslot = lane & 7;

  // hoist per-row gather metadata (row set is kt-invariant)
  int   beg_[4], cnt_[4];
  float invd_[4];
  int   gc[4][4];
  float gv[4][4];
#pragma unroll
  for (int i = 0; i < 4; ++i) {
    const int lr = i * 32 + srow_base;
    int ra = r0 + lr; if (ra > M - 1) ra = M - 1;
    int b = ptrR[ra], e = ptrR[ra + 1];
    if (b < 0) b = 0;
    if (e > nnz) e = nnz;
    if (e < b) e = b;
    int n = e - b;
    beg_[i] = b; cnt_[i] = n;
    float d = deg[ra];
    invd_[i] = (d != 0.f) ? (1.0f / d) : 0.f;
    int c0v = 0;
    if (n > 0) {
      c0v = colsR[b];
      if ((unsigned)c0v >= (unsigned)nColsH) c0v = 0;
    }
#pragma unroll
    for (int p = 0; p < 4; ++p) {
      int c = c0v; float v = 0.f;   // padded entries re-read a hot row with weight 0
      if (p < n) {
        c = colsR[b + p];
        if ((unsigned)c >= (unsigned)nColsH) c = 0;
        v = valsR[b + p];
      }
      gc[i][p] = c; gv[i][p] = v;
    }
  }

  f32x4 acc[4][4];
#pragma unroll
  for (int i = 0; i < 4; ++i)
#pragma unroll
    for (int j = 0; j < 4; ++j)
      acc[i][j] = (f32x4){0.f, 0.f, 0.f, 0.f};

  for (int kt = 0; kt < 8; ++kt) {   // K = 512 = 8 * 64
    const int kb = kt * 64;
#pragma unroll
    for (int i = 0; i < 4; ++i) {
      const int lr = i * 32 + srow_base;
      const int gofs = (sslot ^ (lr & 7)) * 8;
      float a8[8];
#pragma unroll
      for (int t = 0; t < 8; ++t) a8[t] = 0.f;
#pragma unroll
      for (int p = 0; p < 4; ++p) {
        bf16x8 hv = *(const bf16x8*)(H + (size_t)gc[i][p] * CH + kb + gofs);
        float v = gv[i][p];
#pragma unroll
        for (int t = 0; t < 8; ++t) a8[t] += v * (float)hv[t];
      }
      for (int p = 4; p < cnt_[i]; ++p) {   // generic fallback (not taken for deg<=4)
        int c = colsR[beg_[i] + p];
        if ((unsigned)c >= (unsigned)nColsH) c = 0;
        float v = valsR[beg_[i] + p];
        bf16x8 hv = *(const bf16x8*)(H + (size_t)c * CH + kb + gofs);
#pragma unroll
        for (int t = 0; t < 8; ++t) a8[t] += v * (float)hv[t];
      }
      bf16x8 av;
#pragma unroll
      for (int t = 0; t < 8; ++t) av[t] = (bf16_t)(a8[t] * invd_[i]);
      *(bf16x8*)(As + lr * 64 + sslot * 8) = av;
      __builtin_amdgcn_global_load_lds((const __attribute__((address_space(1))) void*)(Bt + (size_t)(c0 + lr) * CH + kb + gofs),
                                       (__attribute__((address_space(3))) void*)(Bs + (i * 32 + wave * 8) * 64), 16, 0, 0);
    }
    __syncthreads();

#pragma unroll
    for (int kk = 0; kk < 2; ++kk) {
      const int slot = (kk * 4 + q) ^ (l16 & 7);
      const int ro = slot * 8;
      bf16x8 af[4], bfv[4];
#pragma unroll
      for (int i = 0; i < 4; ++i)
        af[i] = *(const bf16x8*)(As + (wr + i * 16 + l16) * 64 + ro);
#pragma unroll
      for (int j = 0; j < 4; ++j)
        bfv[j] = *(const bf16x8*)(Bs + (wc + j * 16 + l16) * 64 + ro);
#pragma unroll
      for (int i = 0; i < 4; ++i)
#pragma unroll
        for (int j = 0; j < 4; ++j)
          acc[i][j] = __builtin_amdgcn_mfma_f32_16x16x32_bf16(af[i], bfv[j], acc[i][j], 0, 0, 0);
    }
    __syncthreads();
  }

  const bool f32out = (*flag == 0);
  // C/D layout: col=lane&15, row=(lane>>4)*4+reg  (m89-verified)
#pragma unroll
  for (int i = 0; i < 4; ++i) {
#pragma unroll
    for (int r = 0; r < 4; ++r) {
      int row = r0 + wr + i * 16 + q * 4 + r;
      if (row < M) {
#pragma unroll
        for (int j = 0; j < 4; ++j) {
          int col = c0 + wc + j * 16 + l16;
          float s = fast_sigmoid(acc[i][j][r]);
          if (f32out) ((float*)C)[(size_t)row * CH + col] = s;
          else        ((bf16_t*)C)[(size_t)row * CH + col] = (bf16_t)s;
        }
      }
    }
  }
}

// ---------------- host ----------------
extern "C" void kernel_launch(void* const* d_in, const int* in_sizes, int n_in,
                              void* d_out, int out_size, void* d_ws, size_t ws_size,
                              hipStream_t stream) {
  const void* x    = d_in[0];
  const void* W1   = d_in[1];
  const void* W2   = d_in[2];
  const int*  ei   = (const int*)d_in[3];
  const int*  fi   = (const int*)d_in[4];
  const void* vals = d_in[5];
  const int nnz = in_sizes[3];

  char* ws = (char*)d_ws;
  size_t off = 0;
  auto alloc = [&](size_t bytes) -> void* {
    void* p = ws + off;
    off = (off + bytes + 511) & ~((size_t)511);
    return p;
  };
  // pipeline: t = x@W1 ; h = sig((B2 t)/deg_e) ; out = sig(((B2^T h)/deg_f) @ W2)
  bf16_t* t    = (bf16_t*)alloc((size_t)N_FACES_C * CH * 2);  // 40000 x 512 bf16
  bf16_t* h    = (bf16_t*)alloc((size_t)N_EDGES_C * CH * 2);  // 60000 x 512 bf16
  bf16_t* w1t  = (bf16_t*)alloc((size_t)CH * CH * 2);
  bf16_t* w2t  = (bf16_t*)alloc((size_t)CH * CH * 2);
  float* deg_e = (float*)alloc((size_t)N_EDGES_C * 4);  // --- zeroed block start ---
  float* deg_f = (float*)alloc((size_t)N_FACES_C * 4);
  int*   cnt_e = (int*)alloc((size_t)N_EDGES_C * 4);
  int*   cnt_f = (int*)alloc((size_t)N_FACES_C * 4);
  size_t zero_bytes = (size_t)((char*)cnt_f + (size_t)N_FACES_C * 4 - (char*)deg_e);
  int*   ptr_e = (int*)alloc((size_t)(N_EDGES_C + 1) * 4);
  int*   ptr_f = (int*)alloc((size_t)(N_FACES_C + 1) * 4);
  int*   cur_e = (int*)alloc((size_t)N_EDGES_C * 4);
  int*   cur_f = (int*)alloc((size_t)N_FACES_C * 4);
  int*   col_e = (int*)alloc((size_t)nnz * 4);
  float* val_e = (float*)alloc((size_t)nnz * 4);
  int*   col_f = (int*)alloc((size_t)nnz * 4);
  float* val_f = (float*)alloc((size_t)nnz * 4);
  int*   bsumE = (int*)alloc(64 * 4);
  int*   bsumF = (int*)alloc(64 * 4);
  int*   flag  = (int*)alloc(4);

  detect_dtype<<<1, 64, 0, stream>>>((const unsigned int*)vals, flag);
  hipMemsetAsync(deg_e, 0, zero_bytes, stream);
  count_deg_kernel<<<(nnz + 255) / 256, 256, 0, stream>>>(ei, fi, vals, nnz,
                                                          deg_e, deg_f, cnt_e, cnt_f, flag);

  int nbE = (N_EDGES_C + 1023) / 1024, nbF = (N_FACES_C + 1023) / 1024;
  scan_part2 <<<nbE + nbF, 256, 0, stream>>>(cnt_e, N_EDGES_C, bsumE, cnt_f, N_FACES_C, bsumF, nbE);
  scan_bsums2<<<1, 128, 0, stream>>>(bsumE, nbE, bsumF, nbF);
  scan_final2<<<nbE + nbF, 256, 0, stream>>>(cnt_e, N_EDGES_C, bsumE, ptr_e, cur_e,
                                             cnt_f, N_FACES_C, bsumF, ptr_f, cur_f, nbE);
  csr_fill<<<(nnz + 255) / 256, 256, 0, stream>>>(ei, fi, vals, nnz,
                                                  cur_e, col_e, val_e, cur_f, col_f, val_f, flag);

  transposeW2<<<dim3(16, 16, 2), dim3(32, 8), 0, stream>>>(W1, w1t, W2, w2t, flag);

  // t = x @ W1   [40000 x 512] (f32 A reg-staged -> bf16, or bf16 direct per flag)
  gemm_xw<<<dim3(CH / 128, (N_FACES_C + 127) / 128), 256, 0, stream>>>(x, w1t, t, N_FACES_C, flag);
  // h = sigmoid((B2 t)/deg_e)   [60000 x 512]
  spmm_sig<<<(N_EDGES_C + 3) / 4, 256, 0, stream>>>(ptr_e, col_e, val_e, t, deg_e, h,
                                                    N_EDGES_C, N_FACES_C, nnz);
  // out = sigmoid(((B2^T h)/deg_f) @ W2)  — spmm fused into A-staging
  gemm_gather_sig<<<dim3(CH / 128, (N_FACES_C + 127) / 128), 256, 0, stream>>>(
      ptr_f, col_f, val_f, h, deg_f, w2t, d_out, N_FACES_C, N_EDGES_C, nnz, flag);
}

// Round 2
// 315.032 us; speedup vs baseline: 1.2776x; 1.2776x over previous
//
#include <hip/hip_runtime.h>
#include <cstdint>

#define N_FACES_C 40000
#define N_EDGES_C 60000
#define CH        512

typedef __bf16 bf16_t;
typedef __bf16 bf16x8 __attribute__((ext_vector_type(8)));
typedef float  f32x4  __attribute__((ext_vector_type(4)));
static_assert(sizeof(bf16x8) == 16, "bf16x8 must be 16B");

// ---------------- runtime input-dtype detection ----------------
__global__ void detect_dtype(const unsigned int* __restrict__ vals_bits, int* __restrict__ flag) {
  if (blockIdx.x == 0 && threadIdx.x == 0)
    *flag = (vals_bits[0] == 0x3F803F80u) ? 1 : 0;  // 1 = inputs are bf16
}

__device__ __forceinline__ float load_val(const void* vals, int i, bool isbf16) {
  return isbf16 ? (float)((const bf16_t*)vals)[i] : ((const float*)vals)[i];
}

__device__ __forceinline__ float fast_sigmoid(float z) {
  // v_exp_f32 + v_rcp_f32: ~1ulp each, error ~1e-7 abs on (0,1) — far below bf16 ulp
  float e = __builtin_amdgcn_exp2f(z * -1.44269504f);
  return __builtin_amdgcn_rcpf(1.0f + e);
}

// bijective XCD-chunked block swizzle (m204): blocks with orig%8==k get a contiguous
// wgid range -> column-siblings of one row panel co-locate on one XCD's L2.
__device__ __forceinline__ void swz_block(int gx, int gy, int& obx, int& oby) {
  int orig = blockIdx.y * gx + blockIdx.x;
  int nwg = gx * gy;
  int q = nwg >> 3, r = nwg & 7;
  int xcd = orig & 7, idx = orig >> 3;
  int wg = (xcd < r ? xcd * (q + 1) : r * (q + 1) + (xcd - r) * q) + idx;
  obx = wg % gx;
  oby = wg / gx;
}

// ---------------- degree + count (atomic histogram) ----------------
__global__ void count_deg_kernel(const int* __restrict__ ei, const int* __restrict__ fi,
                                 const void* __restrict__ vals, int nnz,
                                 float* __restrict__ deg_e, float* __restrict__ deg_f,
                                 int* __restrict__ cnt_e, int* __restrict__ cnt_f,
                                 const int* __restrict__ flag) {
  int i = blockIdx.x * 256 + threadIdx.x;
  if (i >= nnz) return;
  bool isb = (*flag != 0);
  float v = load_val(vals, i, isb);
  int e = ei[i], f = fi[i];
  atomicAdd(&deg_e[e], v);
  atomicAdd(&deg_f[f], v);
  atomicAdd(&cnt_e[e], 1);
  atomicAdd(&cnt_f[f], 1);
}

// ---------------- batched 3-phase exclusive scan (e and f in one grid) ----------------
__global__ void scan_part2(const int* __restrict__ cntE, int nE, int* __restrict__ bsumE,
                           const int* __restrict__ cntF, int nF, int* __restrict__ bsumF,
                           int nbE) {
  __shared__ int wsum[4];
  int bx = blockIdx.x;
  const int* cnt; int n; int* bsum; int b;
  if (bx < nbE) { cnt = cntE; n = nE; bsum = bsumE; b = bx; }
  else          { cnt = cntF; n = nF; bsum = bsumF; b = bx - nbE; }
  int t = threadIdx.x;
  int lane = t & 63, wave = t >> 6;
  int base = b * 1024 + t * 4;
  int s = 0;
#pragma unroll
  for (int k = 0; k < 4; ++k) {
    int idx = base + k;
    if (idx < n) s += cnt[idx];
  }
#pragma unroll
  for (int o = 32; o > 0; o >>= 1) s += __shfl_down(s, o);
  if (lane == 0) wsum[wave] = s;
  __syncthreads();
  if (t == 0) bsum[b] = wsum[0] + wsum[1] + wsum[2] + wsum[3];
}

__global__ void scan_bsums2(int* __restrict__ bsumE, int nbE, int* __restrict__ bsumF, int nbF) {
  int wave = threadIdx.x >> 6;          // 0 -> e, 1 -> f
  int lane = threadIdx.x & 63;
  int* bsum = wave ? bsumF : bsumE;
  int nb    = wave ? nbF   : nbE;
  int orig = (lane < nb) ? bsum[lane] : 0;
  int v = orig;
#pragma unroll
  for (int o = 1; o < 64; o <<= 1) {
    int u = __shfl_up(v, o);
    if (lane >= o) v += u;
  }
  if (lane < nb) bsum[lane] = v - orig;  // exclusive
}

__global__ void scan_final2(const int* __restrict__ cntE, int nE, const int* __restrict__ bsumE,
                            int* __restrict__ ptrE, int* __restrict__ curE,
                            const int* __restrict__ cntF, int nF, const int* __restrict__ bsumF,
                            int* __restrict__ ptrF, int* __restrict__ curF, int nbE) {
  __shared__ int wsum[4];
  int bx = blockIdx.x;
  const int* cnt; int n; const int* bsum; int* ptr; int* cur; int b;
  if (bx < nbE) { cnt = cntE; n = nE; bsum = bsumE; ptr = ptrE; cur = curE; b = bx; }
  else          { cnt = cntF; n = nF; bsum = bsumF; ptr = ptrF; cur = curF; b = bx - nbE; }
  int t = threadIdx.x;
  int lane = t & 63, wave = t >> 6;
  int base = b * 1024 + t * 4;
  int c[4];
  int s = 0;
#pragma unroll
  for (int k = 0; k < 4; ++k) {
    int idx = base + k;
    c[k] = (idx < n) ? cnt[idx] : 0;
    s += c[k];
  }
  int v = s;
#pragma unroll
  for (int o = 1; o < 64; o <<= 1) {
    int u = __shfl_up(v, o);
    if (lane >= o) v += u;
  }
  if (lane == 63) wsum[wave] = v;
  __syncthreads();
  int woff = 0;
  for (int w = 0; w < wave; ++w) woff += wsum[w];
  int run = bsum[b] + woff + (v - s);
#pragma unroll
  for (int k = 0; k < 4; ++k) {
    int idx = base + k;
    if (idx < n) {
      ptr[idx] = run;
      cur[idx] = run;
      run += c[k];
      if (idx == n - 1) ptr[n] = run;
    }
  }
}

// ---------------- CSR fill (both directions in one pass) ----------------
__global__ void csr_fill(const int* __restrict__ ei, const int* __restrict__ fi,
                         const void* __restrict__ vals, int nnz,
                         int* __restrict__ cur_e, int* __restrict__ col_e, float* __restrict__ val_e,
                         int* __restrict__ cur_f, int* __restrict__ col_f, float* __restrict__ val_f,
                         const int* __restrict__ flag) {
  int i = blockIdx.x * 256 + threadIdx.x;
  if (i >= nnz) return;
  bool isb = (*flag != 0);
  int e = ei[i], f = fi[i];
  float v = load_val(vals, i, isb);
  int p = atomicAdd(&cur_e[e], 1);
  col_e[p] = f; val_e[p] = v;
  int q = atomicAdd(&cur_f[f], 1);
  col_f[q] = e; val_f[q] = v;
}

// ---------------- 512x512 transpose (both W1 and W2 in one grid via z) ----------------
__global__ void transposeW2(const void* __restrict__ W1, bf16_t* __restrict__ W1t,
                            const void* __restrict__ W2, bf16_t* __restrict__ W2t,
                            const int* __restrict__ flag) {
  __shared__ bf16_t tile[32][33];
  bool isb = (*flag != 0);
  const void* W = blockIdx.z ? W2 : W1;
  bf16_t*    Wt = blockIdx.z ? W2t : W1t;
  int bx = blockIdx.x * 32, by = blockIdx.y * 32;
  int tx = threadIdx.x, ty = threadIdx.y;  // (32, 8)
#pragma unroll
  for (int r = 0; r < 32; r += 8) {
    size_t idx = (size_t)(by + ty + r) * CH + bx + tx;
    tile[ty + r][tx] = isb ? ((const bf16_t*)W)[idx] : (bf16_t)((const float*)W)[idx];
  }
  __syncthreads();
#pragma unroll
  for (int r = 0; r < 32; r += 8)
    Wt[(size_t)(bx + ty + r) * CH + by + tx] = tile[tx][ty + r];
}

// ---------------- CSR-gather SpMM + deg-divide (+ optional sigmoid), bf16 in/out ----------------
// Y[row,:] = act( (sum_p val[p] * X[col[p],:]) / deg[row] )
template <int SIG>
__global__ void spmm_row(const int* __restrict__ ptr, const int* __restrict__ cols,
                         const float* __restrict__ vals, const bf16_t* __restrict__ X,
                         const float* __restrict__ deg, bf16_t* __restrict__ Y,
                         int nRows, int nCols, int nnz) {
  int row = blockIdx.x * 4 + (threadIdx.x >> 6);
  if (row >= nRows) return;
  int lane = threadIdx.x & 63;
  int beg = ptr[row], end = ptr[row + 1];
  if (beg < 0) beg = 0;
  if (end > nnz) end = nnz;
  float acc[8];
#pragma unroll
  for (int t = 0; t < 8; ++t) acc[t] = 0.f;
  const int lofs = lane * 8;
  for (int p = beg; p < end; ++p) {
    int c = cols[p];
    if ((unsigned)c >= (unsigned)nCols) c = 0;
    float v = vals[p];
    bf16x8 xv = *(const bf16x8*)(X + (size_t)c * CH + lofs);
#pragma unroll
    for (int t = 0; t < 8; ++t) acc[t] += v * (float)xv[t];
  }
  float d = deg[row];
  float invd = (d != 0.f) ? (1.0f / d) : 0.f;
  bf16x8 o;
#pragma unroll
  for (int t = 0; t < 8; ++t) {
    float z = acc[t] * invd;
    o[t] = (bf16_t)(SIG ? fast_sigmoid(z) : z);
  }
  *(bf16x8*)(Y + (size_t)row * CH + lofs) = o;
}

// ---------------- GEMM t = A @ Bt^T, A = x (f32 reg-staged+converted, or bf16 direct) ----------
// No activation; bf16 output. LDS row = 64 bf16 = 8 x 16B segs; slot(row,s) = global seg s^(row&7).
__global__ __launch_bounds__(256)
void gemm_xw(const void* __restrict__ A, const bf16_t* __restrict__ Bt,
             bf16_t* __restrict__ C, int M, const int* __restrict__ flag) {
  __shared__ __align__(16) bf16_t As[128 * 64];  // 16 KB
  __shared__ __align__(16) bf16_t Bs[128 * 64];  // 16 KB
  const int tid  = threadIdx.x;
  const int lane = tid & 63;
  const int wave = tid >> 6;
  int bx, by;
  swz_block(gridDim.x, gridDim.y, bx, by);
  const int r0 = by * 128;
  const int c0 = bx * 128;
  const int wr = (wave >> 1) * 64;
  const int wc = (wave & 1) * 64;
  const int q   = lane >> 4;
  const int l16 = lane & 15;
  const int srow_base = wave * 8 + (lane >> 3);
  const int sslot = lane & 7;
  const bool ab = (*flag != 0);  // A already bf16

  f32x4 acc[4][4];
#pragma unroll
  for (int i = 0; i < 4; ++i)
#pragma unroll
    for (int j = 0; j < 4; ++j)
      acc[i][j] = (f32x4){0.f, 0.f, 0.f, 0.f};

  for (int kt = 0; kt < 8; ++kt) {   // K = 512 = 8 * 64
    const int kb = kt * 64;
    if (ab) {
      const bf16_t* Ab = (const bf16_t*)A;
#pragma unroll
      for (int i = 0; i < 4; ++i) {
        const int lr = i * 32 + srow_base;
        const int gofs = (sslot ^ (lr & 7)) * 8;
        int ra = r0 + lr; if (ra > M - 1) ra = M - 1;
        __builtin_amdgcn_global_load_lds((const __attribute__((address_space(1))) void*)(Ab + (size_t)ra * CH + kb + gofs),
                                         (__attribute__((address_space(3))) void*)(As + (i * 32 + wave * 8) * 64), 16, 0, 0);
        __builtin_amdgcn_global_load_lds((const __attribute__((address_space(1))) void*)(Bt + (size_t)(c0 + lr) * CH + kb + gofs),
                                         (__attribute__((address_space(3))) void*)(Bs + (i * 32 + wave * 8) * 64), 16, 0, 0);
      }
    } else {
      const float* Af = (const float*)A;
#pragma unroll
      for (int i = 0; i < 4; ++i) {
        const int lr = i * 32 + srow_base;
        const int gofs = (sslot ^ (lr & 7)) * 8;
        int ra = r0 + lr; if (ra > M - 1) ra = M - 1;
        const float* src = Af + (size_t)ra * CH + kb + gofs;
        float4 a = *(const float4*)src;
        float4 b = *(const float4*)(src + 4);
        bf16x8 v;
        v[0] = (bf16_t)a.x; v[1] = (bf16_t)a.y; v[2] = (bf16_t)a.z; v[3] = (bf16_t)a.w;
        v[4] = (bf16_t)b.x; v[5] = (bf16_t)b.y; v[6] = (bf16_t)b.z; v[7] = (bf16_t)b.w;
        *(bf16x8*)(As + lr * 64 + sslot * 8) = v;
        __builtin_amdgcn_global_load_lds((const __attribute__((address_space(1))) void*)(Bt + (size_t)(c0 + lr) * CH + kb + gofs),
                                         (__attribute__((address_space(3))) void*)(Bs + (i * 32 + wave * 8) * 64), 16, 0, 0);
      }
    }
    __syncthreads();

#pragma unroll
    for (int kk = 0; kk < 2; ++kk) {
      const int slot = (kk * 4 + q) ^ (l16 & 7);
      const int ro = slot * 8;
      bf16x8 af[4], bfv[4];
#pragma unroll
      for (int i = 0; i < 4; ++i)
        af[i] = *(const bf16x8*)(As + (wr + i * 16 + l16) * 64 + ro);
#pragma unroll
      for (int j = 0; j < 4; ++j)
        bfv[j] = *(const bf16x8*)(Bs + (wc + j * 16 + l16) * 64 + ro);
#pragma unroll
      for (int i = 0; i < 4; ++i)
#pragma unroll
        for (int j = 0; j < 4; ++j)
          acc[i][j] = __builtin_amdgcn_mfma_f32_16x16x32_bf16(af[i], bfv[j], acc[i][j], 0, 0, 0);
    }
    __syncthreads();
  }

  // C/D layout: col=lane&15, row=(lane>>4)*4+reg  (m89-verified)
#pragma unroll
  for (int i = 0; i < 4; ++i) {
#pragma unroll
    for (int r = 0; r < 4; ++r) {
      int row = r0 + wr + i * 16 + q * 4 + r;
      if (row < M) {
#pragma unroll
        for (int j = 0; j < 4; ++j) {
          int col = c0 + wc + j * 16 + l16;
          C[(size_t)row * CH + col] = (bf16_t)acc[i][j][r];
        }
      }
    }
  }
}

// ---------------- bf16 GEMM + sigmoid epilogue (final stage), BK=64 ----------------
__global__ __launch_bounds__(256)
void gemm_sig(const bf16_t* __restrict__ A, const bf16_t* __restrict__ Bt,
              void* __restrict__ C, int M,
              const int* __restrict__ flag) {
  __shared__ __align__(16) bf16_t As[128 * 64];  // 16 KB
  __shared__ __align__(16) bf16_t Bs[128 * 64];  // 16 KB
  const int tid  = threadIdx.x;
  const int lane = tid & 63;
  const int wave = tid >> 6;
  int bx, by;
  swz_block(gridDim.x, gridDim.y, bx, by);
  const int r0 = by * 128;
  const int c0 = bx * 128;
  const int wr = (wave >> 1) * 64;
  const int wc = (wave & 1) * 64;
  const int q   = lane >> 4;
  const int l16 = lane & 15;
  const int srow_base = wave * 8 + (lane >> 3);
  const int sslot = lane & 7;

  f32x4 acc[4][4];
#pragma unroll
  for (int i = 0; i < 4; ++i)
#pragma unroll
    for (int j = 0; j < 4; ++j)
      acc[i][j] = (f32x4){0.f, 0.f, 0.f, 0.f};

  for (int kt = 0; kt < 8; ++kt) {
    const int kb = kt * 64;
#pragma unroll
    for (int i = 0; i < 4; ++i) {
      const int lr = i * 32 + srow_base;
      const int gofs = (sslot ^ (lr & 7)) * 8;
      int ra = r0 + lr; if (ra > M - 1) ra = M - 1;
      const bf16_t* ga = A  + (size_t)ra * CH + kb + gofs;
      const bf16_t* gb = Bt + (size_t)(c0 + lr) * CH + kb + gofs;
      __builtin_amdgcn_global_load_lds((const __attribute__((address_space(1))) void*)ga,
                                       (__attribute__((address_space(3))) void*)(As + (i * 32 + wave * 8) * 64), 16, 0, 0);
      __builtin_amdgcn_global_load_lds((const __attribute__((address_space(1))) void*)gb,
                                       (__attribute__((address_space(3))) void*)(Bs + (i * 32 + wave * 8) * 64), 16, 0, 0);
    }
    __syncthreads();

#pragma unroll
    for (int kk = 0; kk < 2; ++kk) {
      const int slot = (kk * 4 + q) ^ (l16 & 7);
      const int ro = slot * 8;
      bf16x8 af[4], bfv[4];
#pragma unroll
      for (int i = 0; i < 4; ++i)
        af[i] = *(const bf16x8*)(As + (wr + i * 16 + l16) * 64 + ro);
#pragma unroll
      for (int j = 0; j < 4; ++j)
        bfv[j] = *(const bf16x8*)(Bs + (wc + j * 16 + l16) * 64 + ro);
#pragma unroll
      for (int i = 0; i < 4; ++i)
#pragma unroll
        for (int j = 0; j < 4; ++j)
          acc[i][j] = __builtin_amdgcn_mfma_f32_16x16x32_bf16(af[i], bfv[j], acc[i][j], 0, 0, 0);
    }
    __syncthreads();
  }

  const bool f32out = (*flag == 0);
  // C/D layout: col=lane&15, row=(lane>>4)*4+reg  (m89-verified)
#pragma unroll
  for (int i = 0; i < 4; ++i) {
#pragma unroll
    for (int r = 0; r < 4; ++r) {
      int row = r0 + wr + i * 16 + q * 4 + r;
      if (row < M) {
#pragma unroll
        for (int j = 0; j < 4; ++j) {
          int col = c0 + wc + j * 16 + l16;
          float s = fast_sigmoid(acc[i][j][r]);
          if (f32out) ((float*)C)[(size_t)row * CH + col] = s;
          else        ((bf16_t*)C)[(size_t)row * CH + col] = (bf16_t)s;
        }
      }
    }
  }
}

// ---------------- host ----------------
extern "C" void kernel_launch(void* const* d_in, const int* in_sizes, int n_in,
                              void* d_out, int out_size, void* d_ws, size_t ws_size,
                              hipStream_t stream) {
  const void* x    = d_in[0];
  const void* W1   = d_in[1];
  const void* W2   = d_in[2];
  const int*  ei   = (const int*)d_in[3];
  const int*  fi   = (const int*)d_in[4];
  const void* vals = d_in[5];
  const int nnz = in_sizes[3];

  char* ws = (char*)d_ws;
  size_t off = 0;
  auto alloc = [&](size_t bytes) -> void* {
    void* p = ws + off;
    off = (off + bytes + 511) & ~((size_t)511);
    return p;
  };
  // pipeline: t = x@W1 ; h = sig((B2 t)/deg_e) ; g = (B2^T h)/deg_f ; out = sig(g@W2)
  bf16_t* t    = (bf16_t*)alloc((size_t)N_FACES_C * CH * 2);  // 40000 x 512 bf16
  bf16_t* h    = (bf16_t*)alloc((size_t)N_EDGES_C * CH * 2);  // 60000 x 512 bf16
  bf16_t* g    = (bf16_t*)alloc((size_t)N_FACES_C * CH * 2);  // 40000 x 512 bf16
  bf16_t* w1t  = (bf16_t*)alloc((size_t)CH * CH * 2);
  bf16_t* w2t  = (bf16_t*)alloc((size_t)CH * CH * 2);
  float* deg_e = (float*)alloc((size_t)N_EDGES_C * 4);  // --- zeroed block start ---
  float* deg_f = (float*)alloc((size_t)N_FACES_C * 4);
  int*   cnt_e = (int*)alloc((size_t)N_EDGES_C * 4);
  int*   cnt_f = (int*)alloc((size_t)N_FACES_C * 4);
  size_t zero_bytes = (size_t)((char*)cnt_f + (size_t)N_FACES_C * 4 - (char*)deg_e);
  int*   ptr_e = (int*)alloc((size_t)(N_EDGES_C + 1) * 4);
  int*   ptr_f = (int*)alloc((size_t)(N_FACES_C + 1) * 4);
  int*   cur_e = (int*)alloc((size_t)N_EDGES_C * 4);
  int*   cur_f = (int*)alloc((size_t)N_FACES_C * 4);
  int*   col_e = (int*)alloc((size_t)nnz * 4);
  float* val_e = (float*)alloc((size_t)nnz * 4);
  int*   col_f = (int*)alloc((size_t)nnz * 4);
  float* val_f = (float*)alloc((size_t)nnz * 4);
  int*   bsumE = (int*)alloc(64 * 4);
  int*   bsumF = (int*)alloc(64 * 4);
  int*   flag  = (int*)alloc(4);

  detect_dtype<<<1, 64, 0, stream>>>((const unsigned int*)vals, flag);
  hipMemsetAsync(deg_e, 0, zero_bytes, stream);
  count_deg_kernel<<<(nnz + 255) / 256, 256, 0, stream>>>(ei, fi, vals, nnz,
                                                          deg_e, deg_f, cnt_e, cnt_f, flag);

  int nbE = (N_EDGES_C + 1023) / 1024, nbF = (N_FACES_C + 1023) / 1024;
  scan_part2 <<<nbE + nbF, 256, 0, stream>>>(cnt_e, N_EDGES_C, bsumE, cnt_f, N_FACES_C, bsumF, nbE);
  scan_bsums2<<<1, 128, 0, stream>>>(bsumE, nbE, bsumF, nbF);
  scan_final2<<<nbE + nbF, 256, 0, stream>>>(cnt_e, N_EDGES_C, bsumE, ptr_e, cur_e,
                                             cnt_f, N_FACES_C, bsumF, ptr_f, cur_f, nbE);
  csr_fill<<<(nnz + 255) / 256, 256, 0, stream>>>(ei, fi, vals, nnz,
                                                  cur_e, col_e, val_e, cur_f, col_f, val_f, flag);

  transposeW2<<<dim3(16, 16, 2), dim3(32, 8), 0, stream>>>(W1, w1t, W2, w2t, flag);

  // t = x @ W1   [40000 x 512] (f32 A reg-staged -> bf16, or bf16 direct per flag)
  gemm_xw<<<dim3(CH / 128, (N_FACES_C + 127) / 128), 256, 0, stream>>>(x, w1t, t, N_FACES_C, flag);
  // h = sigmoid((B2 t)/deg_e)   [60000 x 512]
  spmm_row<1><<<(N_EDGES_C + 3) / 4, 256, 0, stream>>>(ptr_e, col_e, val_e, t, deg_e, h,
                                                       N_EDGES_C, N_FACES_C, nnz);
  // g = (B2^T h)/deg_f   [40000 x 512]
  spmm_row<0><<<(N_FACES_C + 3) / 4, 256, 0, stream>>>(ptr_f, col_f, val_f, h, deg_f, g,
                                                       N_FACES_C, N_EDGES_C, nnz);
  // out = sigmoid(g @ W2)  (dtype per flag)
  gemm_sig<<<dim3(CH / 128, (N_FACES_C + 127) / 128), 256, 0, stream>>>(g, w2t, d_out,
                                                                        N_FACES_C, flag);
}

// Round 3
// 311.273 us; speedup vs baseline: 1.2931x; 1.0121x over previous
//
#include <hip/hip_runtime.h>
#include <cstdint>

#define N_FACES_C 40000
#define N_EDGES_C 60000
#define CH        512

typedef __bf16 bf16_t;
typedef __bf16 bf16x8 __attribute__((ext_vector_type(8)));
typedef float  f32x4  __attribute__((ext_vector_type(4)));
static_assert(sizeof(bf16x8) == 16, "bf16x8 must be 16B");

// ---------------- runtime input-dtype detection ----------------
__global__ void detect_dtype(const unsigned int* __restrict__ vals_bits, int* __restrict__ flag) {
  if (blockIdx.x == 0 && threadIdx.x == 0)
    *flag = (vals_bits[0] == 0x3F803F80u) ? 1 : 0;  // 1 = inputs are bf16
}

__device__ __forceinline__ float load_val(const void* vals, int i, bool isbf16) {
  return isbf16 ? (float)((const bf16_t*)vals)[i] : ((const float*)vals)[i];
}

__device__ __forceinline__ float fast_sigmoid(float z) {
  // v_exp_f32 + v_rcp_f32: ~1ulp each, error ~1e-7 abs on (0,1) — far below bf16 ulp
  float e = __builtin_amdgcn_exp2f(z * -1.44269504f);
  return __builtin_amdgcn_rcpf(1.0f + e);
}

// bijective XCD-chunked block swizzle (m204)
__device__ __forceinline__ void swz_block(int gx, int gy, int& obx, int& oby) {
  int orig = blockIdx.y * gx + blockIdx.x;
  int nwg = gx * gy;
  int q = nwg >> 3, r = nwg & 7;
  int xcd = orig & 7, idx = orig >> 3;
  int wg = (xcd < r ? xcd * (q + 1) : r * (q + 1) + (xcd - r) * q) + idx;
  obx = wg % gx;
  oby = wg / gx;
}

// ---------------- degree + count (atomic histogram) ----------------
__global__ void count_deg_kernel(const int* __restrict__ ei, const int* __restrict__ fi,
                                 const void* __restrict__ vals, int nnz,
                                 float* __restrict__ deg_e, float* __restrict__ deg_f,
                                 int* __restrict__ cnt_e, int* __restrict__ cnt_f,
                                 const int* __restrict__ flag) {
  int i = blockIdx.x * 256 + threadIdx.x;
  if (i >= nnz) return;
  bool isb = (*flag != 0);
  float v = load_val(vals, i, isb);
  int e = ei[i], f = fi[i];
  atomicAdd(&deg_e[e], v);
  atomicAdd(&deg_f[f], v);
  atomicAdd(&cnt_e[e], 1);
  atomicAdd(&cnt_f[f], 1);
}

// ---------------- batched 3-phase exclusive scan (e and f in one grid) ----------------
__global__ void scan_part2(const int* __restrict__ cntE, int nE, int* __restrict__ bsumE,
                           const int* __restrict__ cntF, int nF, int* __restrict__ bsumF,
                           int nbE) {
  __shared__ int wsum[4];
  int bx = blockIdx.x;
  const int* cnt; int n; int* bsum; int b;
  if (bx < nbE) { cnt = cntE; n = nE; bsum = bsumE; b = bx; }
  else          { cnt = cntF; n = nF; bsum = bsumF; b = bx - nbE; }
  int t = threadIdx.x;
  int lane = t & 63, wave = t >> 6;
  int base = b * 1024 + t * 4;
  int s = 0;
#pragma unroll
  for (int k = 0; k < 4; ++k) {
    int idx = base + k;
    if (idx < n) s += cnt[idx];
  }
#pragma unroll
  for (int o = 32; o > 0; o >>= 1) s += __shfl_down(s, o);
  if (lane == 0) wsum[wave] = s;
  __syncthreads();
  if (t == 0) bsum[b] = wsum[0] + wsum[1] + wsum[2] + wsum[3];
}

__global__ void scan_bsums2(int* __restrict__ bsumE, int nbE, int* __restrict__ bsumF, int nbF) {
  int wave = threadIdx.x >> 6;          // 0 -> e, 1 -> f
  int lane = threadIdx.x & 63;
  int* bsum = wave ? bsumF : bsumE;
  int nb    = wave ? nbF   : nbE;
  int orig = (lane < nb) ? bsum[lane] : 0;
  int v = orig;
#pragma unroll
  for (int o = 1; o < 64; o <<= 1) {
    int u = __shfl_up(v, o);
    if (lane >= o) v += u;
  }
  if (lane < nb) bsum[lane] = v - orig;  // exclusive
}

__global__ void scan_final2(const int* __restrict__ cntE, int nE, const int* __restrict__ bsumE,
                            int* __restrict__ ptrE, int* __restrict__ curE,
                            const int* __restrict__ cntF, int nF, const int* __restrict__ bsumF,
                            int* __restrict__ ptrF, int* __restrict__ curF, int nbE) {
  __shared__ int wsum[4];
  int bx = blockIdx.x;
  const int* cnt; int n; const int* bsum; int* ptr; int* cur; int b;
  if (bx < nbE) { cnt = cntE; n = nE; bsum = bsumE; ptr = ptrE; cur = curE; b = bx; }
  else          { cnt = cntF; n = nF; bsum = bsumF; ptr = ptrF; cur = curF; b = bx - nbE; }
  int t = threadIdx.x;
  int lane = t & 63, wave = t >> 6;
  int base = b * 1024 + t * 4;
  int c[4];
  int s = 0;
#pragma unroll
  for (int k = 0; k < 4; ++k) {
    int idx = base + k;
    c[k] = (idx < n) ? cnt[idx] : 0;
    s += c[k];
  }
  int v = s;
#pragma unroll
  for (int o = 1; o < 64; o <<= 1) {
    int u = __shfl_up(v, o);
    if (lane >= o) v += u;
  }
  if (lane == 63) wsum[wave] = v;
  __syncthreads();
  int woff = 0;
  for (int w = 0; w < wave; ++w) woff += wsum[w];
  int run = bsum[b] + woff + (v - s);
#pragma unroll
  for (int k = 0; k < 4; ++k) {
    int idx = base + k;
    if (idx < n) {
      ptr[idx] = run;
      cur[idx] = run;
      run += c[k];
      if (idx == n - 1) ptr[n] = run;
    }
  }
}

// ---------------- CSR fill (both directions in one pass) ----------------
__global__ void csr_fill(const int* __restrict__ ei, const int* __restrict__ fi,
                         const void* __restrict__ vals, int nnz,
                         int* __restrict__ cur_e, int* __restrict__ col_e, float* __restrict__ val_e,
                         int* __restrict__ cur_f, int* __restrict__ col_f, float* __restrict__ val_f,
                         const int* __restrict__ flag) {
  int i = blockIdx.x * 256 + threadIdx.x;
  if (i >= nnz) return;
  bool isb = (*flag != 0);
  int e = ei[i], f = fi[i];
  float v = load_val(vals, i, isb);
  int p = atomicAdd(&cur_e[e], 1);
  col_e[p] = f; val_e[p] = v;
  int q = atomicAdd(&cur_f[f], 1);
  col_f[q] = e; val_f[q] = v;
}

// ---------------- 512x512 transpose (both W1 and W2 in one grid via z) ----------------
__global__ void transposeW2(const void* __restrict__ W1, bf16_t* __restrict__ W1t,
                            const void* __restrict__ W2, bf16_t* __restrict__ W2t,
                            const int* __restrict__ flag) {
  __shared__ bf16_t tile[32][33];
  bool isb = (*flag != 0);
  const void* W = blockIdx.z ? W2 : W1;
  bf16_t*    Wt = blockIdx.z ? W2t : W1t;
  int bx = blockIdx.x * 32, by = blockIdx.y * 32;
  int tx = threadIdx.x, ty = threadIdx.y;  // (32, 8)
#pragma unroll
  for (int r = 0; r < 32; r += 8) {
    size_t idx = (size_t)(by + ty + r) * CH + bx + tx;
    tile[ty + r][tx] = isb ? ((const bf16_t*)W)[idx] : (bf16_t)((const float*)W)[idx];
  }
  __syncthreads();
#pragma unroll
  for (int r = 0; r < 32; r += 8)
    Wt[(size_t)(bx + ty + r) * CH + by + tx] = tile[tx][ty + r];
}

// ---------------- CSR-gather SpMM + deg-divide (+ optional sigmoid), bf16 in/out ----------------
template <int SIG>
__global__ void spmm_row(const int* __restrict__ ptr, const int* __restrict__ cols,
                         const float* __restrict__ vals, const bf16_t* __restrict__ X,
                         const float* __restrict__ deg, bf16_t* __restrict__ Y,
                         int nRows, int nCols, int nnz) {
  int row = blockIdx.x * 4 + (threadIdx.x >> 6);
  if (row >= nRows) return;
  int lane = threadIdx.x & 63;
  int beg = ptr[row], end = ptr[row + 1];
  if (beg < 0) beg = 0;
  if (end > nnz) end = nnz;
  float acc[8];
#pragma unroll
  for (int t = 0; t < 8; ++t) acc[t] = 0.f;
  const int lofs = lane * 8;
  for (int p = beg; p < end; ++p) {
    int c = cols[p];
    if ((unsigned)c >= (unsigned)nCols) c = 0;
    float v = vals[p];
    bf16x8 xv = *(const bf16x8*)(X + (size_t)c * CH + lofs);
#pragma unroll
    for (int t = 0; t < 8; ++t) acc[t] += v * (float)xv[t];
  }
  float d = deg[row];
  float invd = (d != 0.f) ? (1.0f / d) : 0.f;
  bf16x8 o;
#pragma unroll
  for (int t = 0; t < 8; ++t) {
    float z = acc[t] * invd;
    o[t] = (bf16_t)(SIG ? fast_sigmoid(z) : z);
  }
  *(bf16x8*)(Y + (size_t)row * CH + lofs) = o;
}

// ============ 2-phase double-buffered 128x128 GEMM (T3 minimum recipe, m230/m248v2) ============
// Step t: issue STAGE(buf^1, t+1) FIRST (loads in flight), then ds_read+MFMA on buf[cur],
// then ONE __syncthreads per K-step (drains vmcnt for gload_lds + lgkm for ds_write).
// Race-free: writes to buf nb at step t; last reads of nb finished before step t-1's barrier.
// f32-A path = T14 async-split: f32 loads early, cvt+ds_write after the MFMA phase.

// ---- t = A @ W1 (A f32 reg-staged->bf16, or bf16 direct per flag); no activation ----
__global__ __launch_bounds__(256)
void gemm_xw(const void* __restrict__ A, const bf16_t* __restrict__ Bt,
             bf16_t* __restrict__ C, int M, const int* __restrict__ flag) {
  __shared__ __align__(16) bf16_t As[2][128 * 64];  // 2 x 16 KB
  __shared__ __align__(16) bf16_t Bs[2][128 * 64];  // 2 x 16 KB
  const int tid  = threadIdx.x;
  const int lane = tid & 63;
  const int wave = tid >> 6;
  int bx, by;
  swz_block(gridDim.x, gridDim.y, bx, by);
  const int r0 = by * 128;
  const int c0 = bx * 128;
  const int wr = (wave >> 1) * 64;
  const int wc = (wave & 1) * 64;
  const int q   = lane >> 4;
  const int l16 = lane & 15;
  const int srow_base = wave * 8 + (lane >> 3);
  const int sslot = lane & 7;
  const bool ab = (*flag != 0);  // A already bf16

  // per-i staging geometry (kt-invariant)
  int lr_[4], gofs_[4], ra_[4];
#pragma unroll
  for (int i = 0; i < 4; ++i) {
    lr_[i] = i * 32 + srow_base;
    gofs_[i] = (sslot ^ (lr_[i] & 7)) * 8;
    int ra = r0 + lr_[i]; if (ra > M - 1) ra = M - 1;
    ra_[i] = ra;
  }

  f32x4 acc[4][4];
#pragma unroll
  for (int i = 0; i < 4; ++i)
#pragma unroll
    for (int j = 0; j < 4; ++j)
      acc[i][j] = (f32x4){0.f, 0.f, 0.f, 0.f};

  // ---- prologue: stage kt=0 into buf 0 ----
  if (ab) {
    const bf16_t* Ab = (const bf16_t*)A;
#pragma unroll
    for (int i = 0; i < 4; ++i) {
      __builtin_amdgcn_global_load_lds((const __attribute__((address_space(1))) void*)(Ab + (size_t)ra_[i] * CH + gofs_[i]),
                                       (__attribute__((address_space(3))) void*)(As[0] + (i * 32 + wave * 8) * 64), 16, 0, 0);
      __builtin_amdgcn_global_load_lds((const __attribute__((address_space(1))) void*)(Bt + (size_t)(c0 + lr_[i]) * CH + gofs_[i]),
                                       (__attribute__((address_space(3))) void*)(Bs[0] + (i * 32 + wave * 8) * 64), 16, 0, 0);
    }
  } else {
    const float* Af = (const float*)A;
#pragma unroll
    for (int i = 0; i < 4; ++i) {
      const float* src = Af + (size_t)ra_[i] * CH + gofs_[i];
      float4 a = *(const float4*)src;
      float4 b = *(const float4*)(src + 4);
      bf16x8 v;
      v[0] = (bf16_t)a.x; v[1] = (bf16_t)a.y; v[2] = (bf16_t)a.z; v[3] = (bf16_t)a.w;
      v[4] = (bf16_t)b.x; v[5] = (bf16_t)b.y; v[6] = (bf16_t)b.z; v[7] = (bf16_t)b.w;
      *(bf16x8*)(As[0] + lr_[i] * 64 + sslot * 8) = v;
      __builtin_amdgcn_global_load_lds((const __attribute__((address_space(1))) void*)(Bt + (size_t)(c0 + lr_[i]) * CH + gofs_[i]),
                                       (__attribute__((address_space(3))) void*)(Bs[0] + (i * 32 + wave * 8) * 64), 16, 0, 0);
    }
  }
  __syncthreads();

  int cur = 0;
  for (int kt = 0; kt < 8; ++kt) {
    const int nb = cur ^ 1;
    const bool has_next = (kt < 7);
    float4 pa[4], pb[4];
    // ---- stage next tile (loads issued before compute) ----
    if (has_next) {
      const int kb = (kt + 1) * 64;
      if (ab) {
        const bf16_t* Ab = (const bf16_t*)A;
#pragma unroll
        for (int i = 0; i < 4; ++i) {
          __builtin_amdgcn_global_load_lds((const __attribute__((address_space(1))) void*)(Ab + (size_t)ra_[i] * CH + kb + gofs_[i]),
                                           (__attribute__((address_space(3))) void*)(As[nb] + (i * 32 + wave * 8) * 64), 16, 0, 0);
          __builtin_amdgcn_global_load_lds((const __attribute__((address_space(1))) void*)(Bt + (size_t)(c0 + lr_[i]) * CH + kb + gofs_[i]),
                                           (__attribute__((address_space(3))) void*)(Bs[nb] + (i * 32 + wave * 8) * 64), 16, 0, 0);
        }
      } else {
        const float* Af = (const float*)A;
#pragma unroll
        for (int i = 0; i < 4; ++i) {
          const float* src = Af + (size_t)ra_[i] * CH + kb + gofs_[i];
          pa[i] = *(const float4*)src;
          pb[i] = *(const float4*)(src + 4);
        }
#pragma unroll
        for (int i = 0; i < 4; ++i)
          __builtin_amdgcn_global_load_lds((const __attribute__((address_space(1))) void*)(Bt + (size_t)(c0 + lr_[i]) * CH + kb + gofs_[i]),
                                           (__attribute__((address_space(3))) void*)(Bs[nb] + (i * 32 + wave * 8) * 64), 16, 0, 0);
      }
    }
    // ---- compute current tile ----
#pragma unroll
    for (int kk = 0; kk < 2; ++kk) {
      const int slot = (kk * 4 + q) ^ (l16 & 7);
      const int ro = slot * 8;
      bf16x8 af[4], bfv[4];
#pragma unroll
      for (int i = 0; i < 4; ++i)
        af[i] = *(const bf16x8*)(As[cur] + (wr + i * 16 + l16) * 64 + ro);
#pragma unroll
      for (int j = 0; j < 4; ++j)
        bfv[j] = *(const bf16x8*)(Bs[cur] + (wc + j * 16 + l16) * 64 + ro);
#pragma unroll
      for (int i = 0; i < 4; ++i)
#pragma unroll
        for (int j = 0; j < 4; ++j)
          acc[i][j] = __builtin_amdgcn_mfma_f32_16x16x32_bf16(af[i], bfv[j], acc[i][j], 0, 0, 0);
    }
    // ---- late cvt+ds_write for f32-A path (T14: HBM latency hid under MFMAs) ----
    if (has_next && !ab) {
#pragma unroll
      for (int i = 0; i < 4; ++i) {
        bf16x8 v;
        v[0] = (bf16_t)pa[i].x; v[1] = (bf16_t)pa[i].y; v[2] = (bf16_t)pa[i].z; v[3] = (bf16_t)pa[i].w;
        v[4] = (bf16_t)pb[i].x; v[5] = (bf16_t)pb[i].y; v[6] = (bf16_t)pb[i].z; v[7] = (bf16_t)pb[i].w;
        *(bf16x8*)(As[nb] + lr_[i] * 64 + sslot * 8) = v;
      }
    }
    __syncthreads();
    cur = nb;
  }

  // C/D layout: col=lane&15, row=(lane>>4)*4+reg  (m89-verified)
#pragma unroll
  for (int i = 0; i < 4; ++i) {
#pragma unroll
    for (int r = 0; r < 4; ++r) {
      int row = r0 + wr + i * 16 + q * 4 + r;
      if (row < M) {
#pragma unroll
        for (int j = 0; j < 4; ++j) {
          int col = c0 + wc + j * 16 + l16;
          C[(size_t)row * CH + col] = (bf16_t)acc[i][j][r];
        }
      }
    }
  }
}

// ---- out = sigmoid(A @ W2), A bf16; out dtype per flag ----
__global__ __launch_bounds__(256)
void gemm_sig(const bf16_t* __restrict__ A, const bf16_t* __restrict__ Bt,
              void* __restrict__ C, int M, const int* __restrict__ flag) {
  __shared__ __align__(16) bf16_t As[2][128 * 64];
  __shared__ __align__(16) bf16_t Bs[2][128 * 64];
  const int tid  = threadIdx.x;
  const int lane = tid & 63;
  const int wave = tid >> 6;
  int bx, by;
  swz_block(gridDim.x, gridDim.y, bx, by);
  const int r0 = by * 128;
  const int c0 = bx * 128;
  const int wr = (wave >> 1) * 64;
  const int wc = (wave & 1) * 64;
  const int q   = lane >> 4;
  const int l16 = lane & 15;
  const int srow_base = wave * 8 + (lane >> 3);
  const int sslot = lane & 7;

  int lr_[4], gofs_[4], ra_[4];
#pragma unroll
  for (int i = 0; i < 4; ++i) {
    lr_[i] = i * 32 + srow_base;
    gofs_[i] = (sslot ^ (lr_[i] & 7)) * 8;
    int ra = r0 + lr_[i]; if (ra > M - 1) ra = M - 1;
    ra_[i] = ra;
  }

  f32x4 acc[4][4];
#pragma unroll
  for (int i = 0; i < 4; ++i)
#pragma unroll
    for (int j = 0; j < 4; ++j)
      acc[i][j] = (f32x4){0.f, 0.f, 0.f, 0.f};

  // prologue: stage kt=0 into buf 0
#pragma unroll
  for (int i = 0; i < 4; ++i) {
    __builtin_amdgcn_global_load_lds((const __attribute__((address_space(1))) void*)(A + (size_t)ra_[i] * CH + gofs_[i]),
                                     (__attribute__((address_space(3))) void*)(As[0] + (i * 32 + wave * 8) * 64), 16, 0, 0);
    __builtin_amdgcn_global_load_lds((const __attribute__((address_space(1))) void*)(Bt + (size_t)(c0 + lr_[i]) * CH + gofs_[i]),
                                     (__attribute__((address_space(3))) void*)(Bs[0] + (i * 32 + wave * 8) * 64), 16, 0, 0);
  }
  __syncthreads();

  int cur = 0;
  for (int kt = 0; kt < 8; ++kt) {
    const int nb = cur ^ 1;
    if (kt < 7) {
      const int kb = (kt + 1) * 64;
#pragma unroll
      for (int i = 0; i < 4; ++i) {
        __builtin_amdgcn_global_load_lds((const __attribute__((address_space(1))) void*)(A + (size_t)ra_[i] * CH + kb + gofs_[i]),
                                         (__attribute__((address_space(3))) void*)(As[nb] + (i * 32 + wave * 8) * 64), 16, 0, 0);
        __builtin_amdgcn_global_load_lds((const __attribute__((address_space(1))) void*)(Bt + (size_t)(c0 + lr_[i]) * CH + kb + gofs_[i]),
                                         (__attribute__((address_space(3))) void*)(Bs[nb] + (i * 32 + wave * 8) * 64), 16, 0, 0);
      }
    }
#pragma unroll
    for (int kk = 0; kk < 2; ++kk) {
      const int slot = (kk * 4 + q) ^ (l16 & 7);
      const int ro = slot * 8;
      bf16x8 af[4], bfv[4];
#pragma unroll
      for (int i = 0; i < 4; ++i)
        af[i] = *(const bf16x8*)(As[cur] + (wr + i * 16 + l16) * 64 + ro);
#pragma unroll
      for (int j = 0; j < 4; ++j)
        bfv[j] = *(const bf16x8*)(Bs[cur] + (wc + j * 16 + l16) * 64 + ro);
#pragma unroll
      for (int i = 0; i < 4; ++i)
#pragma unroll
        for (int j = 0; j < 4; ++j)
          acc[i][j] = __builtin_amdgcn_mfma_f32_16x16x32_bf16(af[i], bfv[j], acc[i][j], 0, 0, 0);
    }
    __syncthreads();
    cur = nb;
  }

  const bool f32out = (*flag == 0);
  // C/D layout: col=lane&15, row=(lane>>4)*4+reg  (m89-verified)
#pragma unroll
  for (int i = 0; i < 4; ++i) {
#pragma unroll
    for (int r = 0; r < 4; ++r) {
      int row = r0 + wr + i * 16 + q * 4 + r;
      if (row < M) {
#pragma unroll
        for (int j = 0; j < 4; ++j) {
          int col = c0 + wc + j * 16 + l16;
          float s = fast_sigmoid(acc[i][j][r]);
          if (f32out) ((float*)C)[(size_t)row * CH + col] = s;
          else        ((bf16_t*)C)[(size_t)row * CH + col] = (bf16_t)s;
        }
      }
    }
  }
}

// ---------------- host ----------------
extern "C" void kernel_launch(void* const* d_in, const int* in_sizes, int n_in,
                              void* d_out, int out_size, void* d_ws, size_t ws_size,
                              hipStream_t stream) {
  const void* x    = d_in[0];
  const void* W1   = d_in[1];
  const void* W2   = d_in[2];
  const int*  ei   = (const int*)d_in[3];
  const int*  fi   = (const int*)d_in[4];
  const void* vals = d_in[5];
  const int nnz = in_sizes[3];

  char* ws = (char*)d_ws;
  size_t off = 0;
  auto alloc = [&](size_t bytes) -> void* {
    void* p = ws + off;
    off = (off + bytes + 511) & ~((size_t)511);
    return p;
  };
  // pipeline: t = x@W1 ; h = sig((B2 t)/deg_e) ; g = (B2^T h)/deg_f ; out = sig(g@W2)
  bf16_t* t    = (bf16_t*)alloc((size_t)N_FACES_C * CH * 2);  // 40000 x 512 bf16
  bf16_t* h    = (bf16_t*)alloc((size_t)N_EDGES_C * CH * 2);  // 60000 x 512 bf16
  bf16_t* g    = (bf16_t*)alloc((size_t)N_FACES_C * CH * 2);  // 40000 x 512 bf16
  bf16_t* w1t  = (bf16_t*)alloc((size_t)CH * CH * 2);
  bf16_t* w2t  = (bf16_t*)alloc((size_t)CH * CH * 2);
  float* deg_e = (float*)alloc((size_t)N_EDGES_C * 4);  // --- zeroed block start ---
  float* deg_f = (float*)alloc((size_t)N_FACES_C * 4);
  int*   cnt_e = (int*)alloc((size_t)N_EDGES_C * 4);
  int*   cnt_f = (int*)alloc((size_t)N_FACES_C * 4);
  size_t zero_bytes = (size_t)((char*)cnt_f + (size_t)N_FACES_C * 4 - (char*)deg_e);
  int*   ptr_e = (int*)alloc((size_t)(N_EDGES_C + 1) * 4);
  int*   ptr_f = (int*)alloc((size_t)(N_FACES_C + 1) * 4);
  int*   cur_e = (int*)alloc((size_t)N_EDGES_C * 4);
  int*   cur_f = (int*)alloc((size_t)N_FACES_C * 4);
  int*   col_e = (int*)alloc((size_t)nnz * 4);
  float* val_e = (float*)alloc((size_t)nnz * 4);
  int*   col_f = (int*)alloc((size_t)nnz * 4);
  float* val_f = (float*)alloc((size_t)nnz * 4);
  int*   bsumE = (int*)alloc(64 * 4);
  int*   bsumF = (int*)alloc(64 * 4);
  int*   flag  = (int*)alloc(4);

  detect_dtype<<<1, 64, 0, stream>>>((const unsigned int*)vals, flag);
  hipMemsetAsync(deg_e, 0, zero_bytes, stream);
  count_deg_kernel<<<(nnz + 255) / 256, 256, 0, stream>>>(ei, fi, vals, nnz,
                                                          deg_e, deg_f, cnt_e, cnt_f, flag);

  int nbE = (N_EDGES_C + 1023) / 1024, nbF = (N_FACES_C + 1023) / 1024;
  scan_part2 <<<nbE + nbF, 256, 0, stream>>>(cnt_e, N_EDGES_C, bsumE, cnt_f, N_FACES_C, bsumF, nbE);
  scan_bsums2<<<1, 128, 0, stream>>>(bsumE, nbE, bsumF, nbF);
  scan_final2<<<nbE + nbF, 256, 0, stream>>>(cnt_e, N_EDGES_C, bsumE, ptr_e, cur_e,
                                             cnt_f, N_FACES_C, bsumF, ptr_f, cur_f, nbE);
  csr_fill<<<(nnz + 255) / 256, 256, 0, stream>>>(ei, fi, vals, nnz,
                                                  cur_e, col_e, val_e, cur_f, col_f, val_f, flag);

  transposeW2<<<dim3(16, 16, 2), dim3(32, 8), 0, stream>>>(W1, w1t, W2, w2t, flag);

  // t = x @ W1   [40000 x 512]
  gemm_xw<<<dim3(CH / 128, (N_FACES_C + 127) / 128), 256, 0, stream>>>(x, w1t, t, N_FACES_C, flag);
  // h = sigmoid((B2 t)/deg_e)   [60000 x 512]
  spmm_row<1><<<(N_EDGES_C + 3) / 4, 256, 0, stream>>>(ptr_e, col_e, val_e, t, deg_e, h,
                                                       N_EDGES_C, N_FACES_C, nnz);
  // g = (B2^T h)/deg_f   [40000 x 512]
  spmm_row<0><<<(N_FACES_C + 3) / 4, 256, 0, stream>>>(ptr_f, col_f, val_f, h, deg_f, g,
                                                       N_FACES_C, N_EDGES_C, nnz);
  // out = sigmoid(g @ W2)  (dtype per flag)
  gemm_sig<<<dim3(CH / 128, (N_FACES_C + 127) / 128), 256, 0, stream>>>(g, w2t, d_out,
                                                                        N_FACES_C, flag);
}